// Round 10
// baseline (131.130 us; speedup 1.0000x reference)
//
#include <hip/hip_runtime.h>
#include <hip/hip_fp16.h>
#include <math.h>

#define N_NODES 100000
#define N_EDGES 1600000
#define F_DIM 64
#define BSH 9                              // 512 nodes per bucket
#define BNODES 512
#define NBUCK ((N_NODES + BNODES - 1) / BNODES)   // 196
#define CAP 16384                          // slots/bucket (mean 8192, ~90 sigma headroom)
#define EPT 8
#define TILE (256 * EPT)                   // 2048 edges per pass1 block

// ---------------- init bucket cursors ----------------
__global__ __launch_bounds__(256) void init_k(int* __restrict__ bcur) {
    int i = blockIdx.x * 256 + threadIdx.x;
    if (i < NBUCK) bcur[i] = i * CAP;
}

// ---------------- pass1: single-pass bucket scatter (fixed-capacity) ----------------
__global__ __launch_bounds__(256) void pass1_k(const int* __restrict__ src,
                                               const int* __restrict__ dst,
                                               int* __restrict__ bcur,
                                               unsigned int* __restrict__ tmp, int E) {
    __shared__ int lcnt[NBUCK];
    __shared__ int lbase[NBUCK];
    for (int i = threadIdx.x; i < NBUCK; i += 256) lcnt[i] = 0;
    __syncthreads();

    int4 sreg[EPT / 4], dreg[EPT / 4];
    int base4 = blockIdx.x * (TILE / 4);
#pragma unroll
    for (int j = 0; j < EPT / 4; ++j) {
        int i4 = base4 + j * 256 + threadIdx.x;
        if (i4 < E / 4) {
            sreg[j] = ((const int4*)src)[i4];
            dreg[j] = ((const int4*)dst)[i4];
            atomicAdd(&lcnt[dreg[j].x >> BSH], 1);
            atomicAdd(&lcnt[dreg[j].y >> BSH], 1);
            atomicAdd(&lcnt[dreg[j].z >> BSH], 1);
            atomicAdd(&lcnt[dreg[j].w >> BSH], 1);
        } else {
            dreg[j].x = -1;
        }
    }
    __syncthreads();
    for (int b = threadIdx.x; b < NBUCK; b += 256) {
        int c = lcnt[b];
        lbase[b] = c ? atomicAdd(&bcur[b], c) : 0;
        lcnt[b] = 0;
    }
    __syncthreads();
#pragma unroll
    for (int j = 0; j < EPT / 4; ++j) {
        if (dreg[j].x >= 0) {
            int d, s, b, r;
            d = dreg[j].x; s = sreg[j].x; b = d >> BSH;
            r = atomicAdd(&lcnt[b], 1);
            tmp[lbase[b] + r] = (unsigned int)s | ((unsigned int)(d & (BNODES - 1)) << 17);
            d = dreg[j].y; s = sreg[j].y; b = d >> BSH;
            r = atomicAdd(&lcnt[b], 1);
            tmp[lbase[b] + r] = (unsigned int)s | ((unsigned int)(d & (BNODES - 1)) << 17);
            d = dreg[j].z; s = sreg[j].z; b = d >> BSH;
            r = atomicAdd(&lcnt[b], 1);
            tmp[lbase[b] + r] = (unsigned int)s | ((unsigned int)(d & (BNODES - 1)) << 17);
            d = dreg[j].w; s = sreg[j].w; b = d >> BSH;
            r = atomicAdd(&lcnt[b], 1);
            tmp[lbase[b] + r] = (unsigned int)s | ((unsigned int)(d & (BNODES - 1)) << 17);
        }
    }
}

// ---------------- passB (512 thr): per-bucket node sort (in-place), rowinfo, inv ----------------
__global__ __launch_bounds__(512) void passB_k(unsigned int* __restrict__ tmp,  // in: bucketed; out: esrc (in place)
                                               const int* __restrict__ bcur,
                                               unsigned int* __restrict__ rowinfo,
                                               float* __restrict__ inv) {
    __shared__ unsigned int buf[CAP];   // 64 KB
    __shared__ int cnt[BNODES];
    __shared__ int cur[BNODES];
    __shared__ int ls[BNODES];
    int b = blockIdx.x;
    int beg0 = b * CAP;
    int cntb = bcur[b] - beg0;
    int tid = threadIdx.x;

    cnt[tid] = 0;
    __syncthreads();
    for (int i = tid; i < cntb; i += 512) {
        unsigned int v = tmp[beg0 + i];
        buf[i] = v;
        atomicAdd(&cnt[v >> 17], 1);
    }
    __syncthreads();

    int a = cnt[tid];
    ls[tid] = a;
    __syncthreads();
    for (int off = 1; off < BNODES; off <<= 1) {
        int p = (tid >= off) ? ls[tid - off] : 0;
        __syncthreads();
        ls[tid] += p;
        __syncthreads();
    }
    int p0 = beg0 + ls[tid] - a;
    cur[tid] = p0;
    int n = (b << BSH) + tid;
    if (n < N_NODES) {
        rowinfo[n] = (unsigned int)p0 | ((unsigned int)a << 22);
        inv[n] = rsqrtf((float)(a + 1));
    }
    __syncthreads();

    for (int i = tid; i < cntb; i += 512) {
        unsigned int v = buf[i];
        int pos = atomicAdd(&cur[v >> 17], 1);
        tmp[pos] = v & 0x1FFFFu;
    }
}

// ---------------- linear: h_pre = (x*W + b) * inv[n], fp16 [N][64], 128-thr blocks ----------------
__global__ __launch_bounds__(128) void linear_k(const float* __restrict__ x,
                                                const float* __restrict__ W,
                                                const float* __restrict__ bias,
                                                const float* __restrict__ inv,
                                                __half* __restrict__ h, int N) {
    __shared__ float Ws[F_DIM][F_DIM];
    __shared__ float bs[F_DIM];
    for (int i = threadIdx.x; i < F_DIM * F_DIM; i += 128) Ws[i >> 6][i & 63] = W[i];
    if (threadIdx.x < F_DIM) bs[threadIdx.x] = bias[threadIdx.x];
    __syncthreads();

    int n = blockIdx.x * 128 + threadIdx.x;
    if (n >= N) return;

    float xr[F_DIM];
    const float4* xp = (const float4*)(x + (size_t)n * F_DIM);
#pragma unroll
    for (int k4 = 0; k4 < 16; ++k4) {
        float4 v = xp[k4];
        xr[k4 * 4 + 0] = v.x; xr[k4 * 4 + 1] = v.y;
        xr[k4 * 4 + 2] = v.z; xr[k4 * 4 + 3] = v.w;
    }
    float invn = inv[n];
    __half* hp = h + (size_t)n * F_DIM;
#pragma unroll 1
    for (int f0 = 0; f0 < F_DIM; f0 += 4) {
        float a0 = bs[f0 + 0], a1 = bs[f0 + 1], a2 = bs[f0 + 2], a3 = bs[f0 + 3];
#pragma unroll
        for (int k = 0; k < F_DIM; ++k) {
            float xv = xr[k];
            a0 += xv * Ws[k][f0 + 0];
            a1 += xv * Ws[k][f0 + 1];
            a2 += xv * Ws[k][f0 + 2];
            a3 += xv * Ws[k][f0 + 3];
        }
        union { __half2 h2[2]; float2 f2; } u;
        u.h2[0] = __floats2half2_rn(a0 * invn, a1 * invn);
        u.h2[1] = __floats2half2_rn(a2 * invn, a3 * invn);
        *((float2*)(hp + f0)) = u.f2;
    }
}

// ---------------- gelu (tanh approximation, jax.nn.gelu default) ----------------
__device__ __forceinline__ float gelu1(float x) {
    float x3 = x * x * x;
    float t = tanhf(0.7978845608028654f * (x + 0.044715f * x3));
    return 0.5f * x * (1.0f + t);
}

// ---------------- gather: wave/node; 4 edge-slots x 16 lanes; packed fp16 accumulation ----------------
__global__ __launch_bounds__(256) void gather_k(const __half* __restrict__ h,    // h_pre [N][64]
                                                const float* __restrict__ inv,
                                                const unsigned int* __restrict__ rowinfo,
                                                const unsigned int* __restrict__ esrc,
                                                float* __restrict__ out, int N) {
    int n = blockIdx.x * 4 + (threadIdx.x >> 6);
    if (n >= N) return;
    int lane = threadIdx.x & 63;
    int eslot = lane >> 4;      // 0..3: edge slot
    int fq = lane & 15;         // feature quad (halves 4fq..4fq+3)

    unsigned int ri = rowinfo[n];
    int beg = (int)(ri & 0x3FFFFFu);
    int deg = (int)(ri >> 22);

    __half2 acc0 = __floats2half2_rn(0.f, 0.f);
    __half2 acc1 = acc0;
    int k = eslot;
    // unroll 4: 16 edges in flight per wave; fp16 packed adds (no per-term converts)
    for (; k + 12 < deg; k += 16) {
        int s0 = (int)esrc[beg + k];
        int s1 = (int)esrc[beg + k + 4];
        int s2 = (int)esrc[beg + k + 8];
        int s3 = (int)esrc[beg + k + 12];
        union { float2 f; __half2 h2[2]; } u0, u1, u2, u3;
        u0.f = *((const float2*)(h + (size_t)s0 * F_DIM) + fq);
        u1.f = *((const float2*)(h + (size_t)s1 * F_DIM) + fq);
        u2.f = *((const float2*)(h + (size_t)s2 * F_DIM) + fq);
        u3.f = *((const float2*)(h + (size_t)s3 * F_DIM) + fq);
        acc0 = __hadd2(acc0, __hadd2(__hadd2(u0.h2[0], u1.h2[0]), __hadd2(u2.h2[0], u3.h2[0])));
        acc1 = __hadd2(acc1, __hadd2(__hadd2(u0.h2[1], u1.h2[1]), __hadd2(u2.h2[1], u3.h2[1])));
    }
    for (; k < deg; k += 4) {
        int s0 = (int)esrc[beg + k];
        union { float2 f; __half2 h2[2]; } u0;
        u0.f = *((const float2*)(h + (size_t)s0 * F_DIM) + fq);
        acc0 = __hadd2(acc0, u0.h2[0]);
        acc1 = __hadd2(acc1, u0.h2[1]);
    }
    // convert to fp32, reduce across the 4 edge slots
    float2 a = __half22float2(acc0);
    float2 b2 = __half22float2(acc1);
    float ax = a.x, ay = a.y, az = b2.x, aw = b2.y;
    ax += __shfl_xor(ax, 16); ay += __shfl_xor(ay, 16);
    az += __shfl_xor(az, 16); aw += __shfl_xor(aw, 16);
    ax += __shfl_xor(ax, 32); ay += __shfl_xor(ay, 32);
    az += __shfl_xor(az, 32); aw += __shfl_xor(aw, 32);

    if (eslot == 0) {
        float invn = inv[n];
        union { float2 f; __half2 h2[2]; } us;
        us.f = *((const float2*)(h + (size_t)n * F_DIM) + fq);
        float2 s0 = __half22float2(us.h2[0]);
        float2 s1 = __half22float2(us.h2[1]);
        // self: h_pre[n] = h[n]*invn; final *invn gives h[n]*invn^2
        float4 o;
        o.x = gelu1((ax + s0.x) * invn);
        o.y = gelu1((ay + s0.y) * invn);
        o.z = gelu1((az + s1.x) * invn);
        o.w = gelu1((aw + s1.y) * invn);
        ((float4*)(out + (size_t)n * F_DIM))[fq] = o;
    }
}

extern "C" void kernel_launch(void* const* d_in, const int* in_sizes, int n_in,
                              void* d_out, int out_size, void* d_ws, size_t ws_size,
                              hipStream_t stream) {
    const float* x    = (const float*)d_in[0];
    const int*   ei   = (const int*)d_in[1];
    const float* W    = (const float*)d_in[2];
    const float* bias = (const float*)d_in[3];
    float* out = (float*)d_out;

    const int* src = ei;             // edge_index[0]
    const int* dst = ei + N_EDGES;   // edge_index[1]

    // workspace (~26.5 MB)
    unsigned int* tmp     = (unsigned int*)d_ws;              // NBUCK*CAP uints = 12.8 MB (doubles as esrc, in-place)
    unsigned int* rowinfo = tmp + (size_t)NBUCK * CAP;        // N uints
    float*        inv     = (float*)(rowinfo + N_NODES);      // N floats
    int*          bcur    = (int*)(inv + N_NODES);            // NBUCK ints
    size_t off = (size_t)(bcur + NBUCK) - (size_t)d_ws;
    off = (off + 31) & ~(size_t)31;
    __half* h = (__half*)((char*)d_ws + off);                 // N*64 halves = 12.8 MB

    init_k<<<(NBUCK + 255) / 256, 256, 0, stream>>>(bcur);
    pass1_k<<<(N_EDGES + TILE - 1) / TILE, 256, 0, stream>>>(src, dst, bcur, tmp, N_EDGES);
    passB_k<<<NBUCK, 512, 0, stream>>>(tmp, bcur, rowinfo, inv);
    linear_k<<<(N_NODES + 127) / 128, 128, 0, stream>>>(x, W, bias, inv, h, N_NODES);
    gather_k<<<(N_NODES + 3) / 4, 256, 0, stream>>>(h, inv, rowinfo, tmp, out, N_NODES);
}

// Round 11
// 113.655 us; speedup vs baseline: 1.1538x; 1.1538x over previous
//
#include <hip/hip_runtime.h>
#include <hip/hip_fp16.h>
#include <math.h>

#define N_NODES 100000
#define N_EDGES 1600000
#define F_DIM 64
#define BSH 9                              // 512 nodes per bucket
#define BNODES 512
#define NBUCK ((N_NODES + BNODES - 1) / BNODES)   // 196
#define CAP 12288                          // slots/bucket (mean 8163, ~45 sigma headroom)
#define EPT 32
#define TILE (256 * EPT)                   // 8192 edges per pass1 block
#define P1B ((N_EDGES + TILE - 1) / TILE)  // 196
#define LINB ((N_NODES + 255) / 256)       // 391

// ---------------- fused: pass1 (bucket scatter) || linear (h = x*W + b) ----------------
__global__ __launch_bounds__(256) void fused1_k(const int* __restrict__ src,
                                                const int* __restrict__ dst,
                                                int* __restrict__ bcur,            // relative cursors, memset 0
                                                unsigned int* __restrict__ tmp,
                                                const float* __restrict__ x,
                                                const float* __restrict__ W,
                                                const float* __restrict__ bias,
                                                __half* __restrict__ h) {
    if (blockIdx.x < P1B) {
        // ---- pass1 ----
        __shared__ int lcnt[NBUCK];
        __shared__ int lbase[NBUCK];
        for (int i = threadIdx.x; i < NBUCK; i += 256) lcnt[i] = 0;
        __syncthreads();

        int4 sreg[EPT / 4], dreg[EPT / 4];
        int base4 = blockIdx.x * (TILE / 4);
#pragma unroll
        for (int j = 0; j < EPT / 4; ++j) {
            int i4 = base4 + j * 256 + threadIdx.x;
            if (i4 < N_EDGES / 4) {
                sreg[j] = ((const int4*)src)[i4];
                dreg[j] = ((const int4*)dst)[i4];
                atomicAdd(&lcnt[dreg[j].x >> BSH], 1);
                atomicAdd(&lcnt[dreg[j].y >> BSH], 1);
                atomicAdd(&lcnt[dreg[j].z >> BSH], 1);
                atomicAdd(&lcnt[dreg[j].w >> BSH], 1);
            } else {
                dreg[j].x = -1;
            }
        }
        __syncthreads();
        for (int b = threadIdx.x; b < NBUCK; b += 256) {
            int c = lcnt[b];
            lbase[b] = c ? atomicAdd(&bcur[b], c) : 0;   // relative base within bucket
            lcnt[b] = 0;
        }
        __syncthreads();
#pragma unroll
        for (int j = 0; j < EPT / 4; ++j) {
            if (dreg[j].x >= 0) {
                int d, s, b, r;
                d = dreg[j].x; s = sreg[j].x; b = d >> BSH;
                r = atomicAdd(&lcnt[b], 1);
                tmp[(size_t)b * CAP + lbase[b] + r] = (unsigned int)s | ((unsigned int)(d & (BNODES - 1)) << 17);
                d = dreg[j].y; s = sreg[j].y; b = d >> BSH;
                r = atomicAdd(&lcnt[b], 1);
                tmp[(size_t)b * CAP + lbase[b] + r] = (unsigned int)s | ((unsigned int)(d & (BNODES - 1)) << 17);
                d = dreg[j].z; s = sreg[j].z; b = d >> BSH;
                r = atomicAdd(&lcnt[b], 1);
                tmp[(size_t)b * CAP + lbase[b] + r] = (unsigned int)s | ((unsigned int)(d & (BNODES - 1)) << 17);
                d = dreg[j].w; s = sreg[j].w; b = d >> BSH;
                r = atomicAdd(&lcnt[b], 1);
                tmp[(size_t)b * CAP + lbase[b] + r] = (unsigned int)s | ((unsigned int)(d & (BNODES - 1)) << 17);
            }
        }
    } else {
        // ---- linear: h = x*W + b (fp16, no prescale) ----
        __shared__ float Ws[F_DIM][F_DIM];
        __shared__ float bs[F_DIM];
        for (int i = threadIdx.x; i < F_DIM * F_DIM; i += 256) Ws[i >> 6][i & 63] = W[i];
        if (threadIdx.x < F_DIM) bs[threadIdx.x] = bias[threadIdx.x];
        __syncthreads();

        int n = (blockIdx.x - P1B) * 256 + threadIdx.x;
        if (n >= N_NODES) return;

        float xr[F_DIM];
        const float4* xp = (const float4*)(x + (size_t)n * F_DIM);
#pragma unroll
        for (int k4 = 0; k4 < 16; ++k4) {
            float4 v = xp[k4];
            xr[k4 * 4 + 0] = v.x; xr[k4 * 4 + 1] = v.y;
            xr[k4 * 4 + 2] = v.z; xr[k4 * 4 + 3] = v.w;
        }
        __half* hp = h + (size_t)n * F_DIM;
#pragma unroll 1
        for (int f0 = 0; f0 < F_DIM; f0 += 4) {
            float a0 = bs[f0 + 0], a1 = bs[f0 + 1], a2 = bs[f0 + 2], a3 = bs[f0 + 3];
#pragma unroll
            for (int k = 0; k < F_DIM; ++k) {
                float xv = xr[k];
                a0 += xv * Ws[k][f0 + 0];
                a1 += xv * Ws[k][f0 + 1];
                a2 += xv * Ws[k][f0 + 2];
                a3 += xv * Ws[k][f0 + 3];
            }
            union { __half2 h2[2]; float2 f2; } u;
            u.h2[0] = __floats2half2_rn(a0, a1);
            u.h2[1] = __floats2half2_rn(a2, a3);
            *((float2*)(hp + f0)) = u.f2;
        }
    }
}

// ---------------- passB (1024 thr, no LDS staging): sort tmp -> esrc, rowinfo, inv ----------------
__global__ __launch_bounds__(1024) void passB_k(const unsigned int* __restrict__ tmp,
                                                const int* __restrict__ bcur,      // relative counts
                                                unsigned int* __restrict__ esrc,
                                                unsigned int* __restrict__ rowinfo,
                                                float* __restrict__ inv) {
    __shared__ int cnt[BNODES];
    __shared__ int cur[BNODES];
    __shared__ int ls[BNODES];
    int b = blockIdx.x;
    int tid = threadIdx.x;
    int beg0 = b * CAP;
    int cntb = bcur[b];

    if (tid < BNODES) cnt[tid] = 0;
    __syncthreads();
    for (int i = tid; i < cntb; i += 1024)
        atomicAdd(&cnt[tmp[beg0 + i] >> 17], 1);
    __syncthreads();

    int a = 0;
    if (tid < BNODES) { a = cnt[tid]; ls[tid] = a; }
    __syncthreads();
    for (int off = 1; off < BNODES; off <<= 1) {
        int p = 0;
        if (tid < BNODES && tid >= off) p = ls[tid - off];
        __syncthreads();
        if (tid < BNODES) ls[tid] += p;
        __syncthreads();
    }
    if (tid < BNODES) {
        int p0 = beg0 + ls[tid] - a;
        cur[tid] = p0;
        int n = (b << BSH) + tid;
        if (n < N_NODES) {
            rowinfo[n] = (unsigned int)p0 | ((unsigned int)a << 22);
            inv[n] = rsqrtf((float)(a + 1));
        }
    }
    __syncthreads();

    for (int i = tid; i < cntb; i += 1024) {
        unsigned int v = tmp[beg0 + i];
        int pos = atomicAdd(&cur[v >> 17], 1);
        esrc[pos] = v & 0x1FFFFu;
    }
}

// ---------------- gelu (tanh approximation, jax.nn.gelu default) ----------------
__device__ __forceinline__ float gelu1(float x) {
    float x3 = x * x * x;
    float t = tanhf(0.7978845608028654f * (x + 0.044715f * x3));
    return 0.5f * x * (1.0f + t);
}

// ---------------- gather: wave/node; 4 edge-slots x 16 lanes; inv[s] per edge ----------------
__global__ __launch_bounds__(256) void gather_k(const __half* __restrict__ h,    // h [N][64]
                                                const float* __restrict__ inv,
                                                const unsigned int* __restrict__ rowinfo,
                                                const unsigned int* __restrict__ esrc,
                                                float* __restrict__ out, int N) {
    int n = blockIdx.x * 4 + (threadIdx.x >> 6);
    if (n >= N) return;
    int lane = threadIdx.x & 63;
    int eslot = lane >> 4;      // 0..3: edge slot
    int fq = lane & 15;         // feature quad (halves 4fq..4fq+3)

    unsigned int ri = rowinfo[n];
    int beg = (int)(ri & 0x3FFFFFu);
    int deg = (int)(ri >> 22);

    float ax = 0.f, ay = 0.f, az = 0.f, aw = 0.f;
    int k = eslot;
    // unroll 4: 16 edges in flight per wave
    for (; k + 12 < deg; k += 16) {
        int s0 = (int)esrc[beg + k];
        int s1 = (int)esrc[beg + k + 4];
        int s2 = (int)esrc[beg + k + 8];
        int s3 = (int)esrc[beg + k + 12];
        float w0 = inv[s0], w1 = inv[s1], w2 = inv[s2], w3 = inv[s3];
        union { float2 f; __half2 h2[2]; } u0, u1, u2, u3;
        u0.f = *((const float2*)(h + (size_t)s0 * F_DIM) + fq);
        u1.f = *((const float2*)(h + (size_t)s1 * F_DIM) + fq);
        u2.f = *((const float2*)(h + (size_t)s2 * F_DIM) + fq);
        u3.f = *((const float2*)(h + (size_t)s3 * F_DIM) + fq);
        float2 a, b;
        a = __half22float2(u0.h2[0]); b = __half22float2(u0.h2[1]);
        ax = fmaf(a.x, w0, ax); ay = fmaf(a.y, w0, ay); az = fmaf(b.x, w0, az); aw = fmaf(b.y, w0, aw);
        a = __half22float2(u1.h2[0]); b = __half22float2(u1.h2[1]);
        ax = fmaf(a.x, w1, ax); ay = fmaf(a.y, w1, ay); az = fmaf(b.x, w1, az); aw = fmaf(b.y, w1, aw);
        a = __half22float2(u2.h2[0]); b = __half22float2(u2.h2[1]);
        ax = fmaf(a.x, w2, ax); ay = fmaf(a.y, w2, ay); az = fmaf(b.x, w2, az); aw = fmaf(b.y, w2, aw);
        a = __half22float2(u3.h2[0]); b = __half22float2(u3.h2[1]);
        ax = fmaf(a.x, w3, ax); ay = fmaf(a.y, w3, ay); az = fmaf(b.x, w3, az); aw = fmaf(b.y, w3, aw);
    }
    for (; k < deg; k += 4) {
        int s0 = (int)esrc[beg + k];
        float w0 = inv[s0];
        union { float2 f; __half2 h2[2]; } u0;
        u0.f = *((const float2*)(h + (size_t)s0 * F_DIM) + fq);
        float2 a = __half22float2(u0.h2[0]);
        float2 b = __half22float2(u0.h2[1]);
        ax = fmaf(a.x, w0, ax); ay = fmaf(a.y, w0, ay); az = fmaf(b.x, w0, az); aw = fmaf(b.y, w0, aw);
    }
    // reduce across the 4 edge slots
    ax += __shfl_xor(ax, 16); ay += __shfl_xor(ay, 16);
    az += __shfl_xor(az, 16); aw += __shfl_xor(aw, 16);
    ax += __shfl_xor(ax, 32); ay += __shfl_xor(ay, 32);
    az += __shfl_xor(az, 32); aw += __shfl_xor(aw, 32);

    if (eslot == 0) {
        float invn = inv[n];
        union { float2 f; __half2 h2[2]; } us;
        us.f = *((const float2*)(h + (size_t)n * F_DIM) + fq);
        float2 s0 = __half22float2(us.h2[0]);
        float2 s1 = __half22float2(us.h2[1]);
        // out = gelu(invn * (sum_e inv[s]h[s] + invn*h[n]))
        float4 o;
        o.x = gelu1((ax + s0.x * invn) * invn);
        o.y = gelu1((ay + s0.y * invn) * invn);
        o.z = gelu1((az + s1.x * invn) * invn);
        o.w = gelu1((aw + s1.y * invn) * invn);
        ((float4*)(out + (size_t)n * F_DIM))[fq] = o;
    }
}

extern "C" void kernel_launch(void* const* d_in, const int* in_sizes, int n_in,
                              void* d_out, int out_size, void* d_ws, size_t ws_size,
                              hipStream_t stream) {
    const float* x    = (const float*)d_in[0];
    const int*   ei   = (const int*)d_in[1];
    const float* W    = (const float*)d_in[2];
    const float* bias = (const float*)d_in[3];
    float* out = (float*)d_out;

    const int* src = ei;             // edge_index[0]
    const int* dst = ei + N_EDGES;   // edge_index[1]

    // workspace (~33 MB)
    unsigned int* tmp     = (unsigned int*)d_ws;              // NBUCK*CAP uints = 9.6 MB
    unsigned int* esrc    = tmp + (size_t)NBUCK * CAP;        // NBUCK*CAP uints = 9.6 MB
    unsigned int* rowinfo = esrc + (size_t)NBUCK * CAP;       // N uints
    float*        inv     = (float*)(rowinfo + N_NODES);      // N floats
    int*          bcur    = (int*)(inv + N_NODES);            // NBUCK ints
    size_t off = (size_t)(bcur + NBUCK) - (size_t)d_ws;
    off = (off + 31) & ~(size_t)31;
    __half* h = (__half*)((char*)d_ws + off);                 // N*64 halves = 12.8 MB

    hipMemsetAsync(bcur, 0, NBUCK * sizeof(int), stream);

    fused1_k<<<P1B + LINB, 256, 0, stream>>>(src, dst, bcur, tmp, x, W, bias, h);
    passB_k<<<NBUCK, 1024, 0, stream>>>(tmp, bcur, esrc, rowinfo, inv);
    gather_k<<<(N_NODES + 3) / 4, 256, 0, stream>>>(h, inv, rowinfo, esrc, out, N_NODES);
}